// Round 1
// baseline (319.777 us; speedup 1.0000x reference)
//
#include <hip/hip_runtime.h>

// Bidirectional linear RNN (units=1, no bias, linear activation).
//   fw_t = k*x_t + r*fw_{t-1};  bw_t = k*x_t + r*bw_{t+1}
// out0[b,t,:] = (fw, bw); out1 (diff) = zeros.
// R5: fuse the diff-zeroing memset INTO the kernel dispatch as dedicated
// zero-blocks interleaved into the grid (every 3rd block). Removes the
// graph-node dependency edge that serialized 21us of zero-fill ahead of the
// ~37us RNN kernel; both BW-bound streams now run concurrently.
// RNN path itself is byte-identical to R4 (LDS-staged coalesced stores,
// lean shuffle-scan).

constexpr int T_LEN  = 4096;
constexpr int SEG    = 16;
constexpr int NT     = 256;            // threads per block = T_LEN / SEG
constexpr int NW     = NT / 64;        // 4 waves
constexpr int ROW_F4 = T_LEN * 2 / 4;  // 2048 float4 per output row
constexpr int LDS_F4 = (ROW_F4 / 8) * 9;  // 2304 (pad every 8 float4 with 1)

__global__ __launch_bounds__(NT) void bidir_rnn_fused(
    const float* __restrict__ x,     // [B, T]
    const float* __restrict__ kp,    // [1]
    const float* __restrict__ rp,    // [1]
    float*       __restrict__ out,   // [B, T, 2]
    float*       __restrict__ diff,  // [B, T, 2] -> all zeros
    int nZero,                       // number of zero-role blocks
    size_t diff_f4)                  // total float4s in diff
{
    const int bid = blockIdx.x;
    const int tid = threadIdx.x;

    // ---- every 3rd block is a diff-zero block (interleaved so zero-store
    // traffic and rnn traffic saturate HBM concurrently from t=0) ----
    if ((bid % 3) == 2) {
        const int z = bid / 3;
        const float4 zz = make_float4(0.f, 0.f, 0.f, 0.f);
        float4* d4 = (float4*)diff;
        const size_t stride = (size_t)nZero * NT;
        for (size_t i = (size_t)z * NT + tid; i < diff_f4; i += stride)
            d4[i] = zz;                // coalesced: 1 KB/wave/instr
        return;
    }

    // ---- rnn role: bid%3 in {0,1} -> row = bid - bid/3 (bijective 0..B-1) --
    const int b    = bid - bid / 3;
    const int lane = tid & 63;
    const int wv   = tid >> 6;
    const float k = *kp;
    const float r = *rp;

    float pw[SEG + 1];
    pw[0] = 1.0f;
    #pragma unroll
    for (int i = 1; i <= SEG; ++i) pw[i] = pw[i - 1] * r;
    const float a16 = pw[SEG];

    const size_t rowbase = (size_t)b * T_LEN;

    // ---- load 16 contiguous floats (4x float4, per-thread contiguous) ----
    const float4* xin = (const float4*)(x + rowbase) + tid * 4;
    float4 v0 = xin[0], v1 = xin[1], v2 = xin[2], v3 = xin[3];
    float u[SEG] = {v0.x, v0.y, v0.z, v0.w, v1.x, v1.y, v1.z, v1.w,
                    v2.x, v2.y, v2.z, v2.w, v3.x, v3.y, v3.z, v3.w};
    #pragma unroll
    for (int j = 0; j < SEG; ++j) u[j] *= k;

    // ---- local scans: lf forward; backward scan IN PLACE into u (-> lb) ----
    float lf[SEG];
    lf[0] = u[0];
    #pragma unroll
    for (int j = 1; j < SEG; ++j) lf[j] = fmaf(r, lf[j - 1], u[j]);
    #pragma unroll
    for (int j = SEG - 2; j >= 0; --j) u[j] = fmaf(r, u[j + 1], u[j]);
    // u[j] now holds lb[j]

    // ---- forward wave-inclusive (a,b) scan via shfl_up (time = lane asc) ----
    float af = a16, bf = lf[SEG - 1];
    #pragma unroll
    for (int off = 1; off < 64; off <<= 1) {
        float ap = __shfl_up(af, off);
        float bp = __shfl_up(bf, off);
        if (lane >= off) { bf = fmaf(af, bp, bf); af *= ap; }
    }
    float aef = __shfl_up(af, 1), bef = __shfl_up(bf, 1);   // lane-exclusive
    if (lane == 0) { aef = 1.0f; bef = 0.0f; }

    // ---- backward wave-inclusive scan via shfl_down (time = lane desc) ----
    float ab = a16, bb = u[0];
    #pragma unroll
    for (int off = 1; off < 64; off <<= 1) {
        float ap = __shfl_down(ab, off);
        float bp = __shfl_down(bb, off);
        if (lane < 64 - off) { bb = fmaf(ab, bp, bb); ab *= ap; }
    }
    float aeb = __shfl_down(ab, 1), beb = __shfl_down(bb, 1);
    if (lane == 63) { aeb = 1.0f; beb = 0.0f; }

    // ---- cross-wave combine (single barrier, tiny LDS) ----
    __shared__ float4 sOut[LDS_F4];
    __shared__ float sWa[NW], sWb[NW], sVa[NW], sVb[NW];
    if (lane == 63) { sWa[wv] = af; sWb[wv] = bf; }   // fw wave totals
    if (lane == 0)  { sVa[wv] = ab; sVb[wv] = bb; }   // bw wave totals
    __syncthreads();

    float Pb = 0.0f;                       // fw prefix over earlier waves
    #pragma unroll
    for (int w = 0; w < NW - 1; ++w) {
        if (w < wv) { Pb = fmaf(sWa[w], Pb, sWb[w]); }
    }
    const float Hf = fmaf(aef, Pb, bef);   // fw carry into this segment

    float Qb = 0.0f;                       // bw prefix over later waves
    #pragma unroll
    for (int w = NW - 1; w > 0; --w) {
        if (w > wv) { Qb = fmaf(sVa[w], Qb, sVb[w]); }
    }
    const float Hb = fmaf(aeb, Qb, beb);   // bw carry into this segment

    // ---- finalize into LDS (padded float4 layout) ----
    #pragma unroll
    for (int q = 0; q < 8; ++q) {
        const int j0 = 2 * q, j1 = 2 * q + 1;
        float4 o;
        o.x = fmaf(pw[j0 + 1],   Hf, lf[j0]);
        o.y = fmaf(pw[SEG - j0], Hb, u[j0]);
        o.z = fmaf(pw[j1 + 1],   Hf, lf[j1]);
        o.w = fmaf(pw[SEG - j1], Hb, u[j1]);
        sOut[tid * 9 + q] = o;             // flat f4 idx t*8+q -> (f4>>3)*9+(f4&7)
    }
    __syncthreads();

    // ---- truly coalesced stores: 1 KB/wave per instruction ----
    float4* orow = (float4*)(out + rowbase * 2);
    #pragma unroll
    for (int q2 = 0; q2 < 8; ++q2) {
        const int f4 = q2 * NT + tid;
        orow[f4] = sOut[(f4 >> 3) * 9 + (f4 & 7)];
    }
}

extern "C" void kernel_launch(void* const* d_in, const int* in_sizes, int n_in,
                              void* d_out, int out_size, void* d_ws, size_t ws_size,
                              hipStream_t stream) {
    const float* x  = (const float*)d_in[0];
    const float* kp = (const float*)d_in[1];
    const float* rp = (const float*)d_in[2];
    float* out = (float*)d_out;

    const int B = in_sizes[0] / T_LEN;               // 4096
    float* diff = out + (size_t)B * T_LEN * 2;       // second tuple output

    // grid = B rnn blocks + B/2 zero blocks, interleaved 2:1 by blockIdx%3.
    // (B=4096 -> 6144 blocks; zero blocks cover 8,388,608 float4s in exactly
    //  16 coalesced grid-stride iterations each.)
    const int nZ = B / 2;
    const size_t diff_f4 = (size_t)B * T_LEN * 2 / 4;

    bidir_rnn_fused<<<dim3(B + nZ), dim3(NT), 0, stream>>>(
        x, kp, rp, out, diff, nZ, diff_f4);
}

// Round 2
// 316.024 us; speedup vs baseline: 1.0119x; 1.0119x over previous
//
#include <hip/hip_runtime.h>

// Bidirectional linear RNN (units=1, no bias, linear activation).
//   fw_t = k*x_t + r*fw_{t-1};  bw_t = k*x_t + r*bw_{t+1}
// out0[b,t,:] = (fw, bw); out1 (diff) = zeros.
// R6: revert to R4's verified-best RNN path (LDS-staged coalesced stores,
// lean shuffle-scan). Zeroing of diff stays fused in the dispatch but as
// APPENDED tail blocks (bid >= B), not interleaved: execution order matches
// the serial memset schedule (no HBM stream-mixing), while removing the
// graph-node gap and letting zero blocks backfill CUs during RNN ramp-down.
// (R5's interleaved fusion measured +12us, but rocprof showed the harness
// poison fills were 6-10us/fill slower that run — environmental noise.)

constexpr int T_LEN  = 4096;
constexpr int SEG    = 16;
constexpr int NT     = 256;            // threads per block = T_LEN / SEG
constexpr int NW     = NT / 64;        // 4 waves
constexpr int ROW_F4 = T_LEN * 2 / 4;  // 2048 float4 per output row
constexpr int LDS_F4 = (ROW_F4 / 8) * 9;  // 2304 (pad every 8 float4 with 1)

__global__ __launch_bounds__(NT) void bidir_rnn_fused(
    const float* __restrict__ x,     // [B, T]
    const float* __restrict__ kp,    // [1]
    const float* __restrict__ rp,    // [1]
    float*       __restrict__ out,   // [B, T, 2]
    float*       __restrict__ diff,  // [B, T, 2] -> all zeros
    int B,                           // rows (= # rnn blocks)
    int nZero,                       // number of zero-role tail blocks
    size_t diff_f4)                  // total float4s in diff
{
    const int bid = blockIdx.x;
    const int tid = threadIdx.x;

    // ---- tail blocks zero the diff output (replaces hipMemsetAsync node;
    // runs after/overlapping the RNN ramp-down, same order as serial) ----
    if (bid >= B) {
        const int z = bid - B;
        const float4 zz = make_float4(0.f, 0.f, 0.f, 0.f);
        float4* d4 = (float4*)diff;
        const size_t stride = (size_t)nZero * NT;
        for (size_t i = (size_t)z * NT + tid; i < diff_f4; i += stride)
            d4[i] = zz;                // adjacent blocks -> fully coalesced
        return;
    }

    const int b    = bid;
    const int lane = tid & 63;
    const int wv   = tid >> 6;
    const float k = *kp;
    const float r = *rp;

    float pw[SEG + 1];
    pw[0] = 1.0f;
    #pragma unroll
    for (int i = 1; i <= SEG; ++i) pw[i] = pw[i - 1] * r;
    const float a16 = pw[SEG];

    const size_t rowbase = (size_t)b * T_LEN;

    // ---- load 16 contiguous floats (4x float4, per-thread contiguous) ----
    const float4* xin = (const float4*)(x + rowbase) + tid * 4;
    float4 v0 = xin[0], v1 = xin[1], v2 = xin[2], v3 = xin[3];
    float u[SEG] = {v0.x, v0.y, v0.z, v0.w, v1.x, v1.y, v1.z, v1.w,
                    v2.x, v2.y, v2.z, v2.w, v3.x, v3.y, v3.z, v3.w};
    #pragma unroll
    for (int j = 0; j < SEG; ++j) u[j] *= k;

    // ---- local scans: lf forward; backward scan IN PLACE into u (-> lb) ----
    float lf[SEG];
    lf[0] = u[0];
    #pragma unroll
    for (int j = 1; j < SEG; ++j) lf[j] = fmaf(r, lf[j - 1], u[j]);
    #pragma unroll
    for (int j = SEG - 2; j >= 0; --j) u[j] = fmaf(r, u[j + 1], u[j]);
    // u[j] now holds lb[j]

    // ---- forward wave-inclusive (a,b) scan via shfl_up (time = lane asc) ----
    float af = a16, bf = lf[SEG - 1];
    #pragma unroll
    for (int off = 1; off < 64; off <<= 1) {
        float ap = __shfl_up(af, off);
        float bp = __shfl_up(bf, off);
        if (lane >= off) { bf = fmaf(af, bp, bf); af *= ap; }
    }
    float aef = __shfl_up(af, 1), bef = __shfl_up(bf, 1);   // lane-exclusive
    if (lane == 0) { aef = 1.0f; bef = 0.0f; }

    // ---- backward wave-inclusive scan via shfl_down (time = lane desc) ----
    float ab = a16, bb = u[0];
    #pragma unroll
    for (int off = 1; off < 64; off <<= 1) {
        float ap = __shfl_down(ab, off);
        float bp = __shfl_down(bb, off);
        if (lane < 64 - off) { bb = fmaf(ab, bp, bb); ab *= ap; }
    }
    float aeb = __shfl_down(ab, 1), beb = __shfl_down(bb, 1);
    if (lane == 63) { aeb = 1.0f; beb = 0.0f; }

    // ---- cross-wave combine (single barrier, tiny LDS) ----
    __shared__ float4 sOut[LDS_F4];
    __shared__ float sWa[NW], sWb[NW], sVa[NW], sVb[NW];
    if (lane == 63) { sWa[wv] = af; sWb[wv] = bf; }   // fw wave totals
    if (lane == 0)  { sVa[wv] = ab; sVb[wv] = bb; }   // bw wave totals
    __syncthreads();

    float Pb = 0.0f;                       // fw prefix over earlier waves
    #pragma unroll
    for (int w = 0; w < NW - 1; ++w) {
        if (w < wv) { Pb = fmaf(sWa[w], Pb, sWb[w]); }
    }
    const float Hf = fmaf(aef, Pb, bef);   // fw carry into this segment

    float Qb = 0.0f;                       // bw prefix over later waves
    #pragma unroll
    for (int w = NW - 1; w > 0; --w) {
        if (w > wv) { Qb = fmaf(sVa[w], Qb, sVb[w]); }
    }
    const float Hb = fmaf(aeb, Qb, beb);   // bw carry into this segment

    // ---- finalize into LDS (padded float4 layout) ----
    #pragma unroll
    for (int q = 0; q < 8; ++q) {
        const int j0 = 2 * q, j1 = 2 * q + 1;
        float4 o;
        o.x = fmaf(pw[j0 + 1],   Hf, lf[j0]);
        o.y = fmaf(pw[SEG - j0], Hb, u[j0]);
        o.z = fmaf(pw[j1 + 1],   Hf, lf[j1]);
        o.w = fmaf(pw[SEG - j1], Hb, u[j1]);
        sOut[tid * 9 + q] = o;             // flat f4 idx t*8+q -> (f4>>3)*9+(f4&7)
    }
    __syncthreads();

    // ---- truly coalesced stores: 1 KB/wave per instruction ----
    float4* orow = (float4*)(out + rowbase * 2);
    #pragma unroll
    for (int q2 = 0; q2 < 8; ++q2) {
        const int f4 = q2 * NT + tid;
        orow[f4] = sOut[(f4 >> 3) * 9 + (f4 & 7)];
    }
}

extern "C" void kernel_launch(void* const* d_in, const int* in_sizes, int n_in,
                              void* d_out, int out_size, void* d_ws, size_t ws_size,
                              hipStream_t stream) {
    const float* x  = (const float*)d_in[0];
    const float* kp = (const float*)d_in[1];
    const float* rp = (const float*)d_in[2];
    float* out = (float*)d_out;

    const int B = in_sizes[0] / T_LEN;               // 4096
    float* diff = out + (size_t)B * T_LEN * 2;       // second tuple output

    // grid = B rnn blocks + B/2 zero tail blocks.
    // (B=4096 -> 2048 zero blocks covering 8,388,608 float4s in exactly
    //  16 coalesced grid-stride iterations each.)
    const int nZ = B / 2;
    const size_t diff_f4 = (size_t)B * T_LEN * 2 / 4;

    bidir_rnn_fused<<<dim3(B + nZ), dim3(NT), 0, stream>>>(
        x, kp, rp, out, diff, B, nZ, diff_f4);
}

// Round 3
// 307.136 us; speedup vs baseline: 1.0412x; 1.0289x over previous
//
#include <hip/hip_runtime.h>

// Bidirectional linear RNN (units=1, no bias, linear activation).
//   fw_t = k*x_t + r*fw_{t-1};  bw_t = k*x_t + r*bw_{t+1}
// out0[b,t,:] = (fw, bw); out1 (diff) = zeros (via memset node).
// R7: REVERT to verified-best R4. Both fusion topologies for the diff-zeroing
// (R5 interleaved %3, R6 appended tail blocks) measured neutral-to-worse after
// fill-noise correction; the serial hipMemsetAsync + kernel schedule is best.
// Controllable region: memset ~21us + kernel ~37us = 58us vs 51us floor at
// 6.55 TB/s -> remaining headroom ~7us, below harness fill noise (+-6-12us).

constexpr int T_LEN  = 4096;
constexpr int SEG    = 16;
constexpr int NT     = 256;            // threads per block = T_LEN / SEG
constexpr int NW     = NT / 64;        // 4 waves
constexpr int ROW_F4 = T_LEN * 2 / 4;  // 2048 float4 per output row
constexpr int LDS_F4 = (ROW_F4 / 8) * 9;  // 2304 (pad every 8 float4 with 1)

__global__ __launch_bounds__(NT) void bidir_rnn(
    const float* __restrict__ x,     // [B, T]
    const float* __restrict__ kp,    // [1]
    const float* __restrict__ rp,    // [1]
    float*       __restrict__ out)   // [B, T, 2]
{
    const int b    = blockIdx.x;
    const int tid  = threadIdx.x;
    const int lane = tid & 63;
    const int wv   = tid >> 6;
    const float k = *kp;
    const float r = *rp;

    float pw[SEG + 1];
    pw[0] = 1.0f;
    #pragma unroll
    for (int i = 1; i <= SEG; ++i) pw[i] = pw[i - 1] * r;
    const float a16 = pw[SEG];

    const size_t rowbase = (size_t)b * T_LEN;

    // ---- load 16 contiguous floats (4x float4, per-thread contiguous) ----
    const float4* xin = (const float4*)(x + rowbase) + tid * 4;
    float4 v0 = xin[0], v1 = xin[1], v2 = xin[2], v3 = xin[3];
    float u[SEG] = {v0.x, v0.y, v0.z, v0.w, v1.x, v1.y, v1.z, v1.w,
                    v2.x, v2.y, v2.z, v2.w, v3.x, v3.y, v3.z, v3.w};
    #pragma unroll
    for (int j = 0; j < SEG; ++j) u[j] *= k;

    // ---- local scans: lf forward; backward scan IN PLACE into u (-> lb) ----
    float lf[SEG];
    lf[0] = u[0];
    #pragma unroll
    for (int j = 1; j < SEG; ++j) lf[j] = fmaf(r, lf[j - 1], u[j]);
    #pragma unroll
    for (int j = SEG - 2; j >= 0; --j) u[j] = fmaf(r, u[j + 1], u[j]);
    // u[j] now holds lb[j]

    // ---- forward wave-inclusive (a,b) scan via shfl_up (time = lane asc) ----
    float af = a16, bf = lf[SEG - 1];
    #pragma unroll
    for (int off = 1; off < 64; off <<= 1) {
        float ap = __shfl_up(af, off);
        float bp = __shfl_up(bf, off);
        if (lane >= off) { bf = fmaf(af, bp, bf); af *= ap; }
    }
    float aef = __shfl_up(af, 1), bef = __shfl_up(bf, 1);   // lane-exclusive
    if (lane == 0) { aef = 1.0f; bef = 0.0f; }

    // ---- backward wave-inclusive scan via shfl_down (time = lane desc) ----
    float ab = a16, bb = u[0];
    #pragma unroll
    for (int off = 1; off < 64; off <<= 1) {
        float ap = __shfl_down(ab, off);
        float bp = __shfl_down(bb, off);
        if (lane < 64 - off) { bb = fmaf(ab, bp, bb); ab *= ap; }
    }
    float aeb = __shfl_down(ab, 1), beb = __shfl_down(bb, 1);
    if (lane == 63) { aeb = 1.0f; beb = 0.0f; }

    // ---- cross-wave combine (single barrier, tiny LDS) ----
    __shared__ float4 sOut[LDS_F4];
    __shared__ float sWa[NW], sWb[NW], sVa[NW], sVb[NW];
    if (lane == 63) { sWa[wv] = af; sWb[wv] = bf; }   // fw wave totals
    if (lane == 0)  { sVa[wv] = ab; sVb[wv] = bb; }   // bw wave totals
    __syncthreads();

    float Pb = 0.0f;                       // fw prefix over earlier waves
    #pragma unroll
    for (int w = 0; w < NW - 1; ++w) {
        if (w < wv) { Pb = fmaf(sWa[w], Pb, sWb[w]); }
    }
    const float Hf = fmaf(aef, Pb, bef);   // fw carry into this segment

    float Qb = 0.0f;                       // bw prefix over later waves
    #pragma unroll
    for (int w = NW - 1; w > 0; --w) {
        if (w > wv) { Qb = fmaf(sVa[w], Qb, sVb[w]); }
    }
    const float Hb = fmaf(aeb, Qb, beb);   // bw carry into this segment

    // ---- finalize into LDS (padded float4 layout) ----
    #pragma unroll
    for (int q = 0; q < 8; ++q) {
        const int j0 = 2 * q, j1 = 2 * q + 1;
        float4 o;
        o.x = fmaf(pw[j0 + 1],   Hf, lf[j0]);
        o.y = fmaf(pw[SEG - j0], Hb, u[j0]);
        o.z = fmaf(pw[j1 + 1],   Hf, lf[j1]);
        o.w = fmaf(pw[SEG - j1], Hb, u[j1]);
        sOut[tid * 9 + q] = o;             // flat f4 idx t*8+q -> (f4>>3)*9+(f4&7)
    }
    __syncthreads();

    // ---- truly coalesced stores: 1 KB/wave per instruction ----
    float4* orow = (float4*)(out + rowbase * 2);
    #pragma unroll
    for (int q2 = 0; q2 < 8; ++q2) {
        const int f4 = q2 * NT + tid;
        orow[f4] = sOut[(f4 >> 3) * 9 + (f4 & 7)];
    }
}

extern "C" void kernel_launch(void* const* d_in, const int* in_sizes, int n_in,
                              void* d_out, int out_size, void* d_ws, size_t ws_size,
                              hipStream_t stream) {
    const float* x  = (const float*)d_in[0];
    const float* kp = (const float*)d_in[1];
    const float* rp = (const float*)d_in[2];
    float* out = (float*)d_out;

    const int B = in_sizes[0] / T_LEN;               // 4096
    float* diff = out + (size_t)B * T_LEN * 2;       // second tuple output

    // diff == 0 everywhere: offload 134 MB of zero-stores to the fill kernel
    // (graph-capturable memset node, measured ~6.6 TB/s).
    hipMemsetAsync(diff, 0, (size_t)B * T_LEN * 2 * sizeof(float), stream);

    bidir_rnn<<<dim3(B), dim3(NT), 0, stream>>>(x, kp, rp, out);
}